// Round 15
// baseline (82.851 us; speedup 1.0000x reference)
//
#include <hip/hip_runtime.h>

typedef float        f32x4 __attribute__((ext_vector_type(4)));
typedef unsigned int u32x4 __attribute__((ext_vector_type(4)));
typedef unsigned short u16;

// problem dims
#define NB   8
#define NC   512
#define NHW  1024
#define NHEAD 8
#define ND   64

__device__ __forceinline__ u16 f2bf(float f) {
    unsigned u = __builtin_bit_cast(unsigned, f);
    u += 0x7fffu + ((u >> 16) & 1u);          // RNE
    return (u16)(u >> 16);
}

__device__ __forceinline__ void MFMA(f32x4& d, u32x4 a, u32x4 b) {
    asm("v_mfma_f32_16x16x32_bf16 %0, %1, %2, %0" : "+v"(d) : "v"(a), "v"(b));
}

__device__ __forceinline__ unsigned cvtpk_bf16(float lo, float hi) {
    unsigned r;
    asm("v_cvt_pk_bf16_f32 %0, %1, %2" : "=v"(r) : "v"(lo), "v"(hi));
    return r;
}

__device__ __forceinline__ void gload_lds16(const void* g, void* l) {
    __builtin_amdgcn_global_load_lds(
        (const __attribute__((address_space(1))) unsigned int*)g,
        (__attribute__((address_space(3))) unsigned int*)l, 16, 0, 0);
}

// ---------------- prep: gn stats PARTIALS (512 blocks, wide) + weight casts (one launch)
__global__ void k_prep(const float* __restrict__ x, float* __restrict__ stats,
                       const float* __restrict__ qkvw, u16* __restrict__ wqb,
                       const float* __restrict__ pwt,  u16* __restrict__ wpb) {
    const int blk = blockIdx.x;
    if (blk < 512) {
        // partial stats: (b,g) = blk>>3, part = blk&7 covers 8192 floats = 2048 float4
        const float4* p = (const float4*)(x + (size_t)(blk >> 3) * 65536 + (blk & 7) * 8192);
        float s = 0.f, ss = 0.f;
        for (int i = threadIdx.x; i < 2048; i += 256) {
            float4 v = p[i];
            s  += v.x + v.y + v.z + v.w;
            ss += v.x*v.x + v.y*v.y + v.z*v.z + v.w*v.w;
        }
        #pragma unroll
        for (int m = 32; m >= 1; m >>= 1) { s += __shfl_xor(s, m); ss += __shfl_xor(ss, m); }
        __shared__ float ls[4], lss[4];
        const int w = threadIdx.x >> 6;
        if ((threadIdx.x & 63) == 0) { ls[w] = s; lss[w] = ss; }
        __syncthreads();
        if (threadIdx.x == 0)
            ((float2*)stats)[blk] = make_float2(ls[0]+ls[1]+ls[2]+ls[3],
                                                lss[0]+lss[1]+lss[2]+lss[3]);
    } else {
        int i = (blk - 512) * 256 + threadIdx.x;
        const float* in; u16* out;
        if (i < 196608) { in = qkvw; out = wqb; }
        else            { in = pwt;  out = wpb; i -= 196608; }
        float4 v = ((const float4*)in)[i];
        ((ushort4*)out)[i] = make_ushort4(f2bf(v.x), f2bf(v.y), f2bf(v.z), f2bf(v.w));
    }
}

// ------------------------------------------------- normalize + transpose to [b][n][c]
// combines the 8 stats partials inline (fixed order -> deterministic)
__global__ void k_normt(const float* __restrict__ x, const float* __restrict__ gw,
                        const float* __restrict__ gb, const float* __restrict__ stats,
                        u16* __restrict__ xnt) {
    const int cb = blockIdx.x, nb = blockIdx.y, b = blockIdx.z;   // (8,16,8)
    __shared__ float t[64][65];
    const float2* sp = (const float2*)stats + (size_t)(b*8 + cb)*8;
    float S = 0.f, SS = 0.f;
    #pragma unroll
    for (int i = 0; i < 8; ++i) { float2 v = sp[i]; S += v.x; SS += v.y; }
    float mu  = S * (1.f/65536.f);
    float var = SS * (1.f/65536.f) - mu*mu;
    const float2 st = make_float2(mu, rsqrtf(var + 1e-5f));
    const int tx = threadIdx.x & 15, ty = threadIdx.x >> 4;
    const float* xb = x + ((size_t)(b*NC + cb*64))*NHW + nb*64;
    #pragma unroll
    for (int i = 0; i < 4; ++i) {
        int c = ty + i*16;
        float a  = st.y * gw[cb*64 + c];
        float bb = gb[cb*64 + c] - st.x * a;
        float4 v = *(const float4*)(xb + (size_t)c*NHW + tx*4);
        t[c][tx*4+0] = v.x*a + bb;
        t[c][tx*4+1] = v.y*a + bb;
        t[c][tx*4+2] = v.z*a + bb;
        t[c][tx*4+3] = v.w*a + bb;
    }
    __syncthreads();
    u16* ob = xnt + ((size_t)(b*NHW + nb*64))*NC + cb*64;
    #pragma unroll
    for (int i = 0; i < 4; ++i) {
        int n = ty + i*16, c0 = tx*4;
        *(ushort4*)(ob + (size_t)n*NC + c0) =
            make_ushort4(f2bf(t[c0][n]), f2bf(t[c0+1][n]), f2bf(t[c0+2][n]), f2bf(t[c0+3][n]));
    }
}

// ---------------------------------------------------------------- GEMM core (2-phase prefetch)
__device__ __forceinline__ void gemm_core(const u16* __restrict__ A, const u16* __restrict__ Bm,
                                          int Mb, size_t nrowbase,
                                          u16* Asm_, u16* Bsm_, f32x4 (&acc)[4][4]) {
    const int tid = threadIdx.x, wave = tid >> 6, lane = tid & 63;
    const int l15 = lane & 15, l4 = lane >> 4;
    const int wr = wave >> 1, wc = wave & 1;

    auto stage = [&](int kt, int buf) {
        u16* Ab = Asm_ + buf*8192;
        u16* Bb = Bsm_ + buf*8192;
        #pragma unroll
        for (int i = 0; i < 4; ++i) {
            int li  = wave*4 + i;
            int p   = li*64 + lane;
            int row = p >> 3;
            int lc  = (p & 7) ^ (row & 7);
            gload_lds16(A  + (((size_t)(Mb + row)) << 9) + kt*64 + lc*8, Ab + li*512);
            gload_lds16(Bm + ((nrowbase + row)      << 9) + kt*64 + lc*8, Bb + li*512);
        }
    };

    stage(0, 0);
    asm volatile("s_waitcnt vmcnt(0)" ::: "memory");
    __syncthreads();

    for (int kt = 0; kt < 8; ++kt) {
        const int cur = kt & 1;
        if (kt < 7) stage(kt + 1, cur ^ 1);
        const u16* Ab = Asm_ + cur*8192;
        const u16* Bb = Bsm_ + cur*8192;
        u32x4 af[4][2], bf[4][2];
        #pragma unroll
        for (int mt = 0; mt < 4; ++mt)
            #pragma unroll
            for (int ks = 0; ks < 2; ++ks) {
                int ra = wr*64 + mt*16 + l15;
                af[mt][ks] = *(const u32x4*)(Ab + ra*64 + (((l4 + ks*4) ^ (ra & 7)) << 3));
                int rb = wc*64 + mt*16 + l15;
                bf[mt][ks] = *(const u32x4*)(Bb + rb*64 + (((l4 + ks*4) ^ (rb & 7)) << 3));
            }
        __builtin_amdgcn_s_setprio(1);
        #pragma unroll
        for (int mt = 0; mt < 4; ++mt)
            #pragma unroll
            for (int nt = 0; nt < 4; ++nt)
                #pragma unroll
                for (int ks = 0; ks < 2; ++ks)
                    MFMA(acc[mt][nt], af[mt][ks], bf[nt][ks]);
        __builtin_amdgcn_s_setprio(0);
        asm volatile("s_waitcnt vmcnt(0)" ::: "memory");
        __syncthreads();
    }
}

// ---------------------------------------------------------------- QKV GEMM
__global__ __launch_bounds__(256, 2)
void k_gemm_qkv(const u16* __restrict__ wq, const u16* __restrict__ xnt,
                const float* __restrict__ qkvb,
                u16* __restrict__ qb, u16* __restrict__ kb, u16* __restrict__ vtb) {
    __shared__ u16 Asm_[2*128*64], Bsm_[2*128*64];
    f32x4 acc[4][4] = {};
    const int f = blockIdx.x + blockIdx.y*12 + blockIdx.z*96;   // 0..767
    const int pair = f & 63;                                     // XCD = pair%8
    const int Mb  = (f >> 6) * 128;                              // 0..11
    const int Nbl = (pair & 7) * 128;
    const int b   = pair >> 3;
    gemm_core(wq, xnt, Mb, (size_t)(b*NHW + Nbl), Asm_, Bsm_, acc);
    const int tid = threadIdx.x, wave = tid >> 6, lane = tid & 63;
    const int l15 = lane & 15, l4 = lane >> 4;
    const int wr = wave >> 1, wc = wave & 1;
    const float SCL2 = 0.125f * 1.44269504088896f;   // d^-1/2 * log2(e), folded into Q
    #pragma unroll
    for (int mt = 0; mt < 4; ++mt) {
        int ob = Mb + wr*64 + mt*16 + l4*4;
        float4 bi = *(const float4*)(qkvb + ob);
        int t = ob >> 9, oc = ob & 511;
        int hh = oc >> 6, di = oc & 63;
        size_t bh = (size_t)(b*8 + hh);
        float qs = (t == 0) ? SCL2 : 1.f;
        #pragma unroll
        for (int nt = 0; nt < 4; ++nt) {
            int n = Nbl + wc*64 + nt*16 + l15;
            f32x4 a = acc[mt][nt];
            u16 e0 = f2bf((a[0] + bi.x) * qs), e1 = f2bf((a[1] + bi.y) * qs);
            u16 e2 = f2bf((a[2] + bi.z) * qs), e3 = f2bf((a[3] + bi.w) * qs);
            if (t == 0) {
                *(ushort4*)(qb + ((bh*NHW + n)*ND + di)) = make_ushort4(e0, e1, e2, e3);
            } else if (t == 1) {
                *(ushort4*)(kb + ((bh*NHW + n)*ND + di)) = make_ushort4(e0, e1, e2, e3);
            } else {
                u16* p = vtb + ((bh*ND + di)*NHW + n);
                p[0] = e0; p[1024] = e1; p[2048] = e2; p[3072] = e3;
            }
        }
    }
}

// ---------------------------------------------------------------- flash attention
// PROVEN mt=2 PER-WAVE BODY, repartitioned for 2x TLP: 128-thread blocks (2 waves),
// grid (16,8,8) = 1024 blocks -> 4 blocks/CU = 16 waves/CU. LDS exactly 40 KB/block
// (2-buffer K/V + 2-wave Psm). R10-proven 2-buffer schedule (stage(t+1) before
// compute(t), one vmcnt(0)+barrier per tile). XCD swizzle keeps all 16 blocks of
// one (b,h) on the same XCD so the extra staging traffic is L2-local.
__global__ __launch_bounds__(128, 2)
void k_attn(const u16* __restrict__ qg, const u16* __restrict__ kg,
            const u16* __restrict__ vg, u16* __restrict__ og) {
    __shared__ u16 Ksm[2*64*64], Vsm[2*64*64], Psm[2*32*64];
    const int f = blockIdx.x + (blockIdx.y << 4) + (blockIdx.z << 7);  // 0..1023
    const int qt = f >> 6;                                             // 0..15
    const int pair = f & 63;                                           // XCD = f%8 = h
    const int h = pair & 7, b = pair >> 3;
    const int tid = threadIdx.x, wave = tid >> 6, lane = tid & 63;     // wave 0..1
    const int l15 = lane & 15, l4 = lane >> 4;
    const size_t bh = (size_t)(b*8 + h);

    // stage K/V tile kv into buffer bufi (per-wave slice; swizzled via global src)
    auto stage = [&](int kv, int bufi) {
        u16* Kb = Ksm + bufi*4096;
        u16* Vb = Vsm + bufi*4096;
        #pragma unroll
        for (int i = 0; i < 4; ++i) {
            int li = wave*4 + i;
            int p = li*64 + lane;
            int row = p >> 3;
            int lc = (p & 7) ^ (row & 7);
            gload_lds16(kg + (bh*NHW + kv*64 + row)*ND + lc*8, Kb + li*512);
            gload_lds16(vg + (bh*ND + row)*NHW + kv*64 + lc*8, Vb + li*512);
        }
    };

    stage(0, 0);

    // Q fragments (B-operand): lane holds q-col = mt*16+l15, k(d) = ks*32 + l4*8 + j
    const int q0 = qt*64 + wave*32;
    u32x4 qf[2][2];
    #pragma unroll
    for (int mt = 0; mt < 2; ++mt) {
        const u16* qp = qg + (bh*NHW + q0 + mt*16 + l15)*ND + l4*8;
        qf[mt][0] = *(const u32x4*)(qp);
        qf[mt][1] = *(const u32x4*)(qp + 32);
    }
    f32x4 acc[4][2] = {};
    float lrun[2] = {0.f, 0.f};

    asm volatile("s_waitcnt vmcnt(0)" ::: "memory");   // stage(0) DMA complete
    __syncthreads();

    u16* pw = Psm + wave*2048;
    const int psw = (l15 & 7) << 1;                     // even XOR swizzle (8B chunks)

    for (int kv = 0; kv < 16; ++kv) {
        const int cur = kv & 1;
        if (kv < 15) stage(kv + 1, cur ^ 1);
        const u16* Kb = Ksm + cur*4096;
        const u16* Vb = Vsm + cur*4096;

        // S^T = K·Q - 20  (rows: kv, cols: q); Q pre-scaled to log2 domain
        f32x4 sT[4][2];
        __builtin_amdgcn_s_setprio(1);
        #pragma unroll
        for (int ct = 0; ct < 4; ++ct) {
            int m = ct*16 + l15;
            u32x4 kf0 = *(const u32x4*)(Kb + m*64 + ((l4 ^ (m & 7)) << 3));
            u32x4 kf1 = *(const u32x4*)(Kb + m*64 + (((l4 + 4) ^ (m & 7)) << 3));
            #pragma unroll
            for (int mt = 0; mt < 2; ++mt) {
                f32x4 z = {-20.f, -20.f, -20.f, -20.f};
                MFMA(z, kf0, qf[mt][0]);
                MFMA(z, kf1, qf[mt][1]);
                sT[ct][mt] = z;
            }
        }
        __builtin_amdgcn_s_setprio(0);
        // P = exp2(S^T); partial row sums; pack to LDS
        #pragma unroll
        for (int mt = 0; mt < 2; ++mt) {
            float rs = 0.f;
            int prow = mt*16 + l15;
            #pragma unroll
            for (int ct = 0; ct < 4; ++ct) {
                float p0 = __builtin_amdgcn_exp2f(sT[ct][mt][0]);
                float p1 = __builtin_amdgcn_exp2f(sT[ct][mt][1]);
                float p2 = __builtin_amdgcn_exp2f(sT[ct][mt][2]);
                float p3 = __builtin_amdgcn_exp2f(sT[ct][mt][3]);
                rs += (p0 + p1) + (p2 + p3);
                unsigned lo = cvtpk_bf16(p0, p1);
                unsigned hi = cvtpk_bf16(p2, p3);
                int chunk = (ct*4 + l4) ^ psw;
                *(uint2*)(pw + prow*64 + chunk*4) = make_uint2(lo, hi);
            }
            lrun[mt] += rs;
        }
        asm volatile("s_waitcnt lgkmcnt(0)" ::: "memory");
        __builtin_amdgcn_sched_barrier(0);
        // P fragments (B-operand for PV): col=q (l15), k=kv = ks*32 + l4*8 + j
        u32x4 pf[2][2];
        #pragma unroll
        for (int mt = 0; mt < 2; ++mt)
            #pragma unroll
            for (int ks = 0; ks < 2; ++ks) {
                int c0 = (ks*8 + l4*2) ^ psw;
                pf[mt][ks] = *(const u32x4*)(pw + (mt*16 + l15)*64 + c0*4);
            }
        // out^T += V^T · P^T  (A = V^T: row=d, k=kv)
        __builtin_amdgcn_s_setprio(1);
        #pragma unroll
        for (int dt = 0; dt < 4; ++dt) {
            int m = dt*16 + l15;
            u32x4 vf0 = *(const u32x4*)(Vb + m*64 + ((l4 ^ (m & 7)) << 3));
            u32x4 vf1 = *(const u32x4*)(Vb + m*64 + (((l4 + 4) ^ (m & 7)) << 3));
            #pragma unroll
            for (int mt = 0; mt < 2; ++mt) {
                MFMA(acc[dt][mt], vf0, pf[mt][0]);
                MFMA(acc[dt][mt], vf1, pf[mt][1]);
            }
        }
        __builtin_amdgcn_s_setprio(0);
        asm volatile("s_waitcnt vmcnt(0)" ::: "memory");   // own prefetch DMA landed
        __syncthreads();                                   // everyone's prefetch landed
    }
    // finalize: row sums live in l15-groups across l4 -> 2 shfls
    float inv[2];
    #pragma unroll
    for (int mt = 0; mt < 2; ++mt) {
        float l = lrun[mt];
        l += __shfl_xor(l, 16);
        l += __shfl_xor(l, 32);
        inv[mt] = 1.f / l;
    }
    #pragma unroll
    for (int dt = 0; dt < 4; ++dt)
        #pragma unroll
        for (int mt = 0; mt < 2; ++mt) {
            int q = q0 + mt*16 + l15;
            int d = dt*16 + l4*4;
            f32x4 a = acc[dt][mt];
            *(ushort4*)(og + (size_t)(b*NHW + q)*NC + h*ND + d) =
                make_ushort4(f2bf(a[0]*inv[mt]), f2bf(a[1]*inv[mt]),
                             f2bf(a[2]*inv[mt]), f2bf(a[3]*inv[mt]));
        }
}

// ---------------------------------------------------------------- proj GEMM + residual
__global__ __launch_bounds__(256, 2)
void k_gemm_proj(const u16* __restrict__ wp, const u16* __restrict__ att,
                 const float* __restrict__ pb, const float* __restrict__ x,
                 float* __restrict__ out) {
    __shared__ u16 Asm_[2*128*64], Bsm_[2*128*64];
    f32x4 acc[4][4] = {};
    const int f = blockIdx.x + (blockIdx.y << 2) + (blockIdx.z << 5);  // 0..255
    const int pair = f & 63;                                           // XCD = pair%8
    const int Mb  = (f >> 6) * 128;                                    // 0..3
    const int Nbl = (pair & 7) * 128;
    const int b   = pair >> 3;
    gemm_core(wp, att, Mb, (size_t)(b*NHW + Nbl), Asm_, Bsm_, acc);
    const int tid = threadIdx.x, wave = tid >> 6, lane = tid & 63;
    const int l15 = lane & 15, l4 = lane >> 4;
    const int wr = wave >> 1, wc = wave & 1;
    #pragma unroll
    for (int mt = 0; mt < 4; ++mt) {
        int ob = Mb + wr*64 + mt*16 + l4*4;
        float4 bi = *(const float4*)(pb + ob);
        #pragma unroll
        for (int nt = 0; nt < 4; ++nt) {
            int n = Nbl + wc*64 + nt*16 + l15;
            size_t base = ((size_t)(b*NC + ob))*NHW + n;
            out[base]        = acc[mt][nt][0] + bi.x + x[base];
            out[base + 1024] = acc[mt][nt][1] + bi.y + x[base + 1024];
            out[base + 2048] = acc[mt][nt][2] + bi.z + x[base + 2048];
            out[base + 3072] = acc[mt][nt][3] + bi.w + x[base + 3072];
        }
    }
}

// ---------------------------------------------------------------- launcher
extern "C" void kernel_launch(void* const* d_in, const int* in_sizes, int n_in,
                              void* d_out, int out_size, void* d_ws, size_t ws_size,
                              hipStream_t stream) {
    (void)in_sizes; (void)n_in; (void)out_size; (void)ws_size;
    const float* x    = (const float*)d_in[0];
    const float* gw   = (const float*)d_in[1];
    const float* gb   = (const float*)d_in[2];
    const float* qkvw = (const float*)d_in[3];
    const float* qkvb = (const float*)d_in[4];
    const float* pw   = (const float*)d_in[5];
    const float* pbv  = (const float*)d_in[6];
    float* out = (float*)d_out;
    char* ws = (char*)d_ws;

    constexpr size_t oWQ  = 4096;   // stats partials: 512 float2 = 4 KB
    constexpr size_t oWP  = oWQ  + (size_t)1536*512*2;
    constexpr size_t oXNT = oWP  + (size_t)512*512*2;
    constexpr size_t oQ   = oXNT + (size_t)NB*NHW*NC*2;
    constexpr size_t oK   = oQ   + (size_t)NB*NHEAD*NHW*ND*2;
    constexpr size_t oVT  = oK   + (size_t)NB*NHEAD*NHW*ND*2;

    float* stats = (float*)ws;
    u16* wqb = (u16*)(ws + oWQ);
    u16* wpb = (u16*)(ws + oWP);
    u16* xnt = (u16*)(ws + oXNT);
    u16* qb  = (u16*)(ws + oQ);
    u16* kb  = (u16*)(ws + oK);
    u16* vtb = (u16*)(ws + oVT);
    u16* att = xnt;   // xnT dead after QKV GEMM; reuse for attention output

    k_prep<<<1536, 256, 0, stream>>>(x, stats, qkvw, wqb, pw, wpb);
    k_normt<<<dim3(8,16,8), 256, 0, stream>>>(x, gw, gb, stats, xnt);
    k_gemm_qkv<<<dim3(12,8,8), 256, 0, stream>>>(wqb, xnt, qkvb, qb, kb, vtb);
    k_attn<<<dim3(16,8,8), 128, 0, stream>>>(qb, kb, vtb, att);
    k_gemm_proj<<<dim3(4,8,8), 256, 0, stream>>>(wpb, att, pbv, x, out);
}

// Round 17
// 82.186 us; speedup vs baseline: 1.0081x; 1.0081x over previous
//
#include <hip/hip_runtime.h>

typedef float        f32x4 __attribute__((ext_vector_type(4)));
typedef unsigned int u32x4 __attribute__((ext_vector_type(4)));
typedef unsigned short u16;

// problem dims
#define NB   8
#define NC   512
#define NHW  1024
#define NHEAD 8
#define ND   64

__device__ __forceinline__ u16 f2bf(float f) {
    unsigned u = __builtin_bit_cast(unsigned, f);
    u += 0x7fffu + ((u >> 16) & 1u);          // RNE
    return (u16)(u >> 16);
}

__device__ __forceinline__ void MFMA(f32x4& d, u32x4 a, u32x4 b) {
    asm("v_mfma_f32_16x16x32_bf16 %0, %1, %2, %0" : "+v"(d) : "v"(a), "v"(b));
}

__device__ __forceinline__ unsigned cvtpk_bf16(float lo, float hi) {
    unsigned r;
    asm("v_cvt_pk_bf16_f32 %0, %1, %2" : "=v"(r) : "v"(lo), "v"(hi));
    return r;
}

__device__ __forceinline__ void gload_lds16(const void* g, void* l) {
    __builtin_amdgcn_global_load_lds(
        (const __attribute__((address_space(1))) unsigned int*)g,
        (__attribute__((address_space(3))) unsigned int*)l, 16, 0, 0);
}

// ---------------- prep: gn stats PARTIALS (512 blocks, wide) + weight casts (one launch)
__global__ void k_prep(const float* __restrict__ x, float* __restrict__ stats,
                       const float* __restrict__ qkvw, u16* __restrict__ wqb,
                       const float* __restrict__ pwt,  u16* __restrict__ wpb) {
    const int blk = blockIdx.x;
    if (blk < 512) {
        // partial stats: (b,g) = blk>>3, part = blk&7 covers 8192 floats = 2048 float4
        const float4* p = (const float4*)(x + (size_t)(blk >> 3) * 65536 + (blk & 7) * 8192);
        float s = 0.f, ss = 0.f;
        for (int i = threadIdx.x; i < 2048; i += 256) {
            float4 v = p[i];
            s  += v.x + v.y + v.z + v.w;
            ss += v.x*v.x + v.y*v.y + v.z*v.z + v.w*v.w;
        }
        #pragma unroll
        for (int m = 32; m >= 1; m >>= 1) { s += __shfl_xor(s, m); ss += __shfl_xor(ss, m); }
        __shared__ float ls[4], lss[4];
        const int w = threadIdx.x >> 6;
        if ((threadIdx.x & 63) == 0) { ls[w] = s; lss[w] = ss; }
        __syncthreads();
        if (threadIdx.x == 0)
            ((float2*)stats)[blk] = make_float2(ls[0]+ls[1]+ls[2]+ls[3],
                                                lss[0]+lss[1]+lss[2]+lss[3]);
    } else {
        int i = (blk - 512) * 256 + threadIdx.x;
        const float* in; u16* out;
        if (i < 196608) { in = qkvw; out = wqb; }
        else            { in = pwt;  out = wpb; i -= 196608; }
        float4 v = ((const float4*)in)[i];
        ((ushort4*)out)[i] = make_ushort4(f2bf(v.x), f2bf(v.y), f2bf(v.z), f2bf(v.w));
    }
}

// ------------------------------------------------- normalize + transpose to [b][n][c]
// combines the 8 stats partials inline (fixed order -> deterministic)
__global__ void k_normt(const float* __restrict__ x, const float* __restrict__ gw,
                        const float* __restrict__ gb, const float* __restrict__ stats,
                        u16* __restrict__ xnt) {
    const int cb = blockIdx.x, nb = blockIdx.y, b = blockIdx.z;   // (8,16,8)
    __shared__ float t[64][65];
    const float2* sp = (const float2*)stats + (size_t)(b*8 + cb)*8;
    float S = 0.f, SS = 0.f;
    #pragma unroll
    for (int i = 0; i < 8; ++i) { float2 v = sp[i]; S += v.x; SS += v.y; }
    float mu  = S * (1.f/65536.f);
    float var = SS * (1.f/65536.f) - mu*mu;
    const float2 st = make_float2(mu, rsqrtf(var + 1e-5f));
    const int tx = threadIdx.x & 15, ty = threadIdx.x >> 4;
    const float* xb = x + ((size_t)(b*NC + cb*64))*NHW + nb*64;
    #pragma unroll
    for (int i = 0; i < 4; ++i) {
        int c = ty + i*16;
        float a  = st.y * gw[cb*64 + c];
        float bb = gb[cb*64 + c] - st.x * a;
        float4 v = *(const float4*)(xb + (size_t)c*NHW + tx*4);
        t[c][tx*4+0] = v.x*a + bb;
        t[c][tx*4+1] = v.y*a + bb;
        t[c][tx*4+2] = v.z*a + bb;
        t[c][tx*4+3] = v.w*a + bb;
    }
    __syncthreads();
    u16* ob = xnt + ((size_t)(b*NHW + nb*64))*NC + cb*64;
    #pragma unroll
    for (int i = 0; i < 4; ++i) {
        int n = ty + i*16, c0 = tx*4;
        *(ushort4*)(ob + (size_t)n*NC + c0) =
            make_ushort4(f2bf(t[c0][n]), f2bf(t[c0+1][n]), f2bf(t[c0+2][n]), f2bf(t[c0+3][n]));
    }
}

// ---------------------------------------------------------------- GEMM core (2-phase prefetch)
__device__ __forceinline__ void gemm_core(const u16* __restrict__ A, const u16* __restrict__ Bm,
                                          int Mb, size_t nrowbase,
                                          u16* Asm_, u16* Bsm_, f32x4 (&acc)[4][4]) {
    const int tid = threadIdx.x, wave = tid >> 6, lane = tid & 63;
    const int l15 = lane & 15, l4 = lane >> 4;
    const int wr = wave >> 1, wc = wave & 1;

    auto stage = [&](int kt, int buf) {
        u16* Ab = Asm_ + buf*8192;
        u16* Bb = Bsm_ + buf*8192;
        #pragma unroll
        for (int i = 0; i < 4; ++i) {
            int li  = wave*4 + i;
            int p   = li*64 + lane;
            int row = p >> 3;
            int lc  = (p & 7) ^ (row & 7);
            gload_lds16(A  + (((size_t)(Mb + row)) << 9) + kt*64 + lc*8, Ab + li*512);
            gload_lds16(Bm + ((nrowbase + row)      << 9) + kt*64 + lc*8, Bb + li*512);
        }
    };

    stage(0, 0);
    asm volatile("s_waitcnt vmcnt(0)" ::: "memory");
    __syncthreads();

    for (int kt = 0; kt < 8; ++kt) {
        const int cur = kt & 1;
        if (kt < 7) stage(kt + 1, cur ^ 1);
        const u16* Ab = Asm_ + cur*8192;
        const u16* Bb = Bsm_ + cur*8192;
        u32x4 af[4][2], bf[4][2];
        #pragma unroll
        for (int mt = 0; mt < 4; ++mt)
            #pragma unroll
            for (int ks = 0; ks < 2; ++ks) {
                int ra = wr*64 + mt*16 + l15;
                af[mt][ks] = *(const u32x4*)(Ab + ra*64 + (((l4 + ks*4) ^ (ra & 7)) << 3));
                int rb = wc*64 + mt*16 + l15;
                bf[mt][ks] = *(const u32x4*)(Bb + rb*64 + (((l4 + ks*4) ^ (rb & 7)) << 3));
            }
        __builtin_amdgcn_s_setprio(1);
        #pragma unroll
        for (int mt = 0; mt < 4; ++mt)
            #pragma unroll
            for (int nt = 0; nt < 4; ++nt)
                #pragma unroll
                for (int ks = 0; ks < 2; ++ks)
                    MFMA(acc[mt][nt], af[mt][ks], bf[nt][ks]);
        __builtin_amdgcn_s_setprio(0);
        asm volatile("s_waitcnt vmcnt(0)" ::: "memory");
        __syncthreads();
    }
}

// ---------------------------------------------------------------- QKV GEMM
__global__ __launch_bounds__(256, 2)
void k_gemm_qkv(const u16* __restrict__ wq, const u16* __restrict__ xnt,
                const float* __restrict__ qkvb,
                u16* __restrict__ qb, u16* __restrict__ kb, u16* __restrict__ vtb) {
    __shared__ u16 Asm_[2*128*64], Bsm_[2*128*64];
    f32x4 acc[4][4] = {};
    const int f = blockIdx.x + blockIdx.y*12 + blockIdx.z*96;   // 0..767
    const int pair = f & 63;                                     // XCD = pair%8
    const int Mb  = (f >> 6) * 128;                              // 0..11
    const int Nbl = (pair & 7) * 128;
    const int b   = pair >> 3;
    gemm_core(wq, xnt, Mb, (size_t)(b*NHW + Nbl), Asm_, Bsm_, acc);
    const int tid = threadIdx.x, wave = tid >> 6, lane = tid & 63;
    const int l15 = lane & 15, l4 = lane >> 4;
    const int wr = wave >> 1, wc = wave & 1;
    const float SCL2 = 0.125f * 1.44269504088896f;   // d^-1/2 * log2(e), folded into Q
    #pragma unroll
    for (int mt = 0; mt < 4; ++mt) {
        int ob = Mb + wr*64 + mt*16 + l4*4;
        float4 bi = *(const float4*)(qkvb + ob);
        int t = ob >> 9, oc = ob & 511;
        int hh = oc >> 6, di = oc & 63;
        size_t bh = (size_t)(b*8 + hh);
        float qs = (t == 0) ? SCL2 : 1.f;
        #pragma unroll
        for (int nt = 0; nt < 4; ++nt) {
            int n = Nbl + wc*64 + nt*16 + l15;
            f32x4 a = acc[mt][nt];
            u16 e0 = f2bf((a[0] + bi.x) * qs), e1 = f2bf((a[1] + bi.y) * qs);
            u16 e2 = f2bf((a[2] + bi.z) * qs), e3 = f2bf((a[3] + bi.w) * qs);
            if (t == 0) {
                *(ushort4*)(qb + ((bh*NHW + n)*ND + di)) = make_ushort4(e0, e1, e2, e3);
            } else if (t == 1) {
                *(ushort4*)(kb + ((bh*NHW + n)*ND + di)) = make_ushort4(e0, e1, e2, e3);
            } else {
                u16* p = vtb + ((bh*ND + di)*NHW + n);
                p[0] = e0; p[1024] = e1; p[2048] = e2; p[3072] = e3;
            }
        }
    }
}

// ---------------------------------------------------------------- flash attention
// R12/R14-PASSED STRUCTURE exactly (mt=2, 3-buffer K/V prefetch 2 deep, counted
// vmcnt(4), XCD swizzle, s_setprio). mt>=4 / pair-unroll RETIRED: 5 failures
// (R5,R6,R7,R13,R16) across asm AND builtin MFMA — undiagnosed, do not retry.
__global__ __launch_bounds__(256, 2)
void k_attn(const u16* __restrict__ qg, const u16* __restrict__ kg,
            const u16* __restrict__ vg, u16* __restrict__ og) {
    __shared__ u16 Ksm[3*64*64], Vsm[3*64*64], Psm[4*32*64];
    const int f = blockIdx.x + (blockIdx.y << 3) + (blockIdx.z << 6);  // 0..511
    const int qt = f >> 6;                                             // 0..7
    const int pair = f & 63;                                           // XCD = pair%8
    const int h = pair & 7, b = pair >> 3;
    const int tid = threadIdx.x, wave = tid >> 6, lane = tid & 63;
    const int l15 = lane & 15, l4 = lane >> 4;
    const size_t bh = (size_t)(b*8 + h);

    // stage K/V tile kv into buffer bufi (per-wave slice; swizzled via global src)
    auto stage = [&](int kv, int bufi) {
        u16* Kb = Ksm + bufi*4096;
        u16* Vb = Vsm + bufi*4096;
        #pragma unroll
        for (int i = 0; i < 2; ++i) {
            int li = wave*2 + i;
            int p = li*64 + lane;
            int row = p >> 3;
            int lc = (p & 7) ^ (row & 7);
            gload_lds16(kg + (bh*NHW + kv*64 + row)*ND + lc*8, Kb + li*512);
            gload_lds16(vg + (bh*ND + row)*NHW + kv*64 + lc*8, Vb + li*512);
        }
    };

    stage(0, 0);
    stage(1, 1);

    // Q fragments (B-operand): lane holds q-col = mt*16+l15, k(d) = ks*32 + l4*8 + j
    const int q0 = qt*128 + wave*32;
    u32x4 qf[2][2];
    #pragma unroll
    for (int mt = 0; mt < 2; ++mt) {
        const u16* qp = qg + (bh*NHW + q0 + mt*16 + l15)*ND + l4*8;
        qf[mt][0] = *(const u32x4*)(qp);
        qf[mt][1] = *(const u32x4*)(qp + 32);
    }
    f32x4 acc[4][2] = {};
    float lrun[2] = {0.f, 0.f};

    u16* pw = Psm + wave*2048;
    const int psw = (l15 & 7) << 1;                     // even XOR swizzle (8B chunks)

    int bufc = 0;                                        // kv % 3
    for (int kv = 0; kv < 16; ++kv) {
        // drain own stage(kv); stage(kv+1)'s 4 DMAs may stay in flight
        if (kv < 15) { asm volatile("s_waitcnt vmcnt(4)" ::: "memory"); }
        else         { asm volatile("s_waitcnt vmcnt(0)" ::: "memory"); }
        __syncthreads();   // all waves' tile-kv slices landed; compute(kv-1) done everywhere
        if (kv < 14) {
            int bn = bufc + 2; if (bn >= 3) bn -= 3;
            stage(kv + 2, bn);
        }
        const u16* Kb = Ksm + bufc*4096;
        const u16* Vb = Vsm + bufc*4096;

        // S^T = K·Q - 20  (rows: kv, cols: q); Q pre-scaled to log2 domain
        f32x4 sT[4][2];
        __builtin_amdgcn_s_setprio(1);
        #pragma unroll
        for (int ct = 0; ct < 4; ++ct) {
            int m = ct*16 + l15;
            u32x4 kf0 = *(const u32x4*)(Kb + m*64 + ((l4 ^ (m & 7)) << 3));
            u32x4 kf1 = *(const u32x4*)(Kb + m*64 + (((l4 + 4) ^ (m & 7)) << 3));
            #pragma unroll
            for (int mt = 0; mt < 2; ++mt) {
                f32x4 z = {-20.f, -20.f, -20.f, -20.f};
                MFMA(z, kf0, qf[mt][0]);
                MFMA(z, kf1, qf[mt][1]);
                sT[ct][mt] = z;
            }
        }
        __builtin_amdgcn_s_setprio(0);
        // P = exp2(S^T); partial row sums; pack to LDS
        #pragma unroll
        for (int mt = 0; mt < 2; ++mt) {
            float rs = 0.f;
            int prow = mt*16 + l15;
            #pragma unroll
            for (int ct = 0; ct < 4; ++ct) {
                float p0 = __builtin_amdgcn_exp2f(sT[ct][mt][0]);
                float p1 = __builtin_amdgcn_exp2f(sT[ct][mt][1]);
                float p2 = __builtin_amdgcn_exp2f(sT[ct][mt][2]);
                float p3 = __builtin_amdgcn_exp2f(sT[ct][mt][3]);
                rs += (p0 + p1) + (p2 + p3);
                unsigned lo = cvtpk_bf16(p0, p1);
                unsigned hi = cvtpk_bf16(p2, p3);
                int chunk = (ct*4 + l4) ^ psw;
                *(uint2*)(pw + prow*64 + chunk*4) = make_uint2(lo, hi);
            }
            lrun[mt] += rs;
        }
        asm volatile("s_waitcnt lgkmcnt(0)" ::: "memory");
        __builtin_amdgcn_sched_barrier(0);
        // P fragments (B-operand for PV): col=q (l15), k=kv = ks*32 + l4*8 + j
        u32x4 pf[2][2];
        #pragma unroll
        for (int mt = 0; mt < 2; ++mt)
            #pragma unroll
            for (int ks = 0; ks < 2; ++ks) {
                int c0 = (ks*8 + l4*2) ^ psw;
                pf[mt][ks] = *(const u32x4*)(pw + (mt*16 + l15)*64 + c0*4);
            }
        // out^T += V^T · P^T  (A = V^T: row=d, k=kv)
        __builtin_amdgcn_s_setprio(1);
        #pragma unroll
        for (int dt = 0; dt < 4; ++dt) {
            int m = dt*16 + l15;
            u32x4 vf0 = *(const u32x4*)(Vb + m*64 + ((l4 ^ (m & 7)) << 3));
            u32x4 vf1 = *(const u32x4*)(Vb + m*64 + (((l4 + 4) ^ (m & 7)) << 3));
            #pragma unroll
            for (int mt = 0; mt < 2; ++mt) {
                MFMA(acc[dt][mt], vf0, pf[mt][0]);
                MFMA(acc[dt][mt], vf1, pf[mt][1]);
            }
        }
        __builtin_amdgcn_s_setprio(0);
        bufc += 1; if (bufc >= 3) bufc = 0;
    }
    // finalize: row sums live in l15-groups across l4 -> 2 shfls
    float inv[2];
    #pragma unroll
    for (int mt = 0; mt < 2; ++mt) {
        float l = lrun[mt];
        l += __shfl_xor(l, 16);
        l += __shfl_xor(l, 32);
        inv[mt] = 1.f / l;
    }
    #pragma unroll
    for (int dt = 0; dt < 4; ++dt)
        #pragma unroll
        for (int mt = 0; mt < 2; ++mt) {
            int q = q0 + mt*16 + l15;
            int d = dt*16 + l4*4;
            f32x4 a = acc[dt][mt];
            *(ushort4*)(og + (size_t)(b*NHW + q)*NC + h*ND + d) =
                make_ushort4(f2bf(a[0]*inv[mt]), f2bf(a[1]*inv[mt]),
                             f2bf(a[2]*inv[mt]), f2bf(a[3]*inv[mt]));
        }
}

// ---------------------------------------------------------------- proj GEMM + residual
__global__ __launch_bounds__(256, 2)
void k_gemm_proj(const u16* __restrict__ wp, const u16* __restrict__ att,
                 const float* __restrict__ pb, const float* __restrict__ x,
                 float* __restrict__ out) {
    __shared__ u16 Asm_[2*128*64], Bsm_[2*128*64];
    f32x4 acc[4][4] = {};
    const int f = blockIdx.x + (blockIdx.y << 2) + (blockIdx.z << 5);  // 0..255
    const int pair = f & 63;                                           // XCD = pair%8
    const int Mb  = (f >> 6) * 128;                                    // 0..3
    const int Nbl = (pair & 7) * 128;
    const int b   = pair >> 3;
    gemm_core(wp, att, Mb, (size_t)(b*NHW + Nbl), Asm_, Bsm_, acc);
    const int tid = threadIdx.x, wave = tid >> 6, lane = tid & 63;
    const int l15 = lane & 15, l4 = lane >> 4;
    const int wr = wave >> 1, wc = wave & 1;
    #pragma unroll
    for (int mt = 0; mt < 4; ++mt) {
        int ob = Mb + wr*64 + mt*16 + l4*4;
        float4 bi = *(const float4*)(pb + ob);
        #pragma unroll
        for (int nt = 0; nt < 4; ++nt) {
            int n = Nbl + wc*64 + nt*16 + l15;
            size_t base = ((size_t)(b*NC + ob))*NHW + n;
            out[base]        = acc[mt][nt][0] + bi.x + x[base];
            out[base + 1024] = acc[mt][nt][1] + bi.y + x[base + 1024];
            out[base + 2048] = acc[mt][nt][2] + bi.z + x[base + 2048];
            out[base + 3072] = acc[mt][nt][3] + bi.w + x[base + 3072];
        }
    }
}

// ---------------------------------------------------------------- launcher
extern "C" void kernel_launch(void* const* d_in, const int* in_sizes, int n_in,
                              void* d_out, int out_size, void* d_ws, size_t ws_size,
                              hipStream_t stream) {
    (void)in_sizes; (void)n_in; (void)out_size; (void)ws_size;
    const float* x    = (const float*)d_in[0];
    const float* gw   = (const float*)d_in[1];
    const float* gb   = (const float*)d_in[2];
    const float* qkvw = (const float*)d_in[3];
    const float* qkvb = (const float*)d_in[4];
    const float* pw   = (const float*)d_in[5];
    const float* pbv  = (const float*)d_in[6];
    float* out = (float*)d_out;
    char* ws = (char*)d_ws;

    constexpr size_t oWQ  = 4096;   // stats partials: 512 float2 = 4 KB
    constexpr size_t oWP  = oWQ  + (size_t)1536*512*2;
    constexpr size_t oXNT = oWP  + (size_t)512*512*2;
    constexpr size_t oQ   = oXNT + (size_t)NB*NHW*NC*2;
    constexpr size_t oK   = oQ   + (size_t)NB*NHEAD*NHW*ND*2;
    constexpr size_t oVT  = oK   + (size_t)NB*NHEAD*NHW*ND*2;

    float* stats = (float*)ws;
    u16* wqb = (u16*)(ws + oWQ);
    u16* wpb = (u16*)(ws + oWP);
    u16* xnt = (u16*)(ws + oXNT);
    u16* qb  = (u16*)(ws + oQ);
    u16* kb  = (u16*)(ws + oK);
    u16* vtb = (u16*)(ws + oVT);
    u16* att = xnt;   // xnT dead after QKV GEMM; reuse for attention output

    k_prep<<<1536, 256, 0, stream>>>(x, stats, qkvw, wqb, pw, wpb);
    k_normt<<<dim3(8,16,8), 256, 0, stream>>>(x, gw, gb, stats, xnt);
    k_gemm_qkv<<<dim3(12,8,8), 256, 0, stream>>>(wqb, xnt, qkvb, qb, kb, vtb);
    k_attn<<<dim3(8,8,8), 256, 0, stream>>>(qb, kb, vtb, att);
    k_gemm_proj<<<dim3(4,8,8), 256, 0, stream>>>(wpb, att, pbv, x, out);
}